// Round 1
// baseline (227.083 us; speedup 1.0000x reference)
//
#include <hip/hip_runtime.h>

// DataPreprocessor: interleave even/odd row planes then extract 16x16 patches.
// out[b, z1*32+z2, p*16+q] = in[b, parity, k*512 + c]
//   where r = 16*z1 + p, c = 16*z2 + q, parity = r & 1, k = r >> 1.
// Pure permutation, memory-bound. All moves done as float4 (16B) units:
// 16 consecutive output floats == 16 contiguous input floats.

__global__ __launch_bounds__(256) void DataPreprocessor_60739427500336_kernel(
    const float4* __restrict__ in, float4* __restrict__ out) {
    int t = blockIdx.x * blockDim.x + threadIdx.x;   // one float4 per thread
    int idx = t << 2;                                // flat float index into out

    // Decompose output flat index: idx = (((b*512 + z1*32 + z2)*16 + p)*16 + q)
    int q     = idx & 15;           // multiple of 4 (idx = t*4)
    int p     = (idx >> 4) & 15;
    int patch = (idx >> 8) & 511;   // z1*32 + z2
    int b     = idx >> 17;
    int z2    = patch & 31;
    int z1    = patch >> 5;

    int r = (z1 << 4) + p;          // source row in the interleaved matrix R
    int c = (z2 << 4) + q;          // source col (16B aligned)
    int parity = r & 1;             // which input plane
    int k = r >> 1;                 // row within the plane

    // input flat float index: b*(2*65536) + parity*65536 + k*512 + c
    int in_idx = (b << 17) + (parity << 16) + (k << 9) + c;

    out[t] = in[in_idx >> 2];
}

extern "C" void kernel_launch(void* const* d_in, const int* in_sizes, int n_in,
                              void* d_out, int out_size, void* d_ws, size_t ws_size,
                              hipStream_t stream) {
    const float4* in = (const float4*)d_in[0];
    float4* out = (float4*)d_out;
    // total floats = 256 * 2 * 65536 = 33,554,432 -> 8,388,608 float4s
    const int n_vec4 = 256 * 2 * 65536 / 4;
    const int block = 256;
    const int grid = n_vec4 / block;  // 32768
    DataPreprocessor_60739427500336_kernel<<<grid, block, 0, stream>>>(in, out);
}